// Round 20
// baseline (110.409 us; speedup 1.0000x reference)
//
#include <hip/hip_runtime.h>
#include <math.h>

namespace {

constexpr int SOUT = 12;    // (14-3)/1+1
constexpr int OCAP = 32;
constexpr int PD   = 16;    // 4x4 pose
constexpr int NI   = 288;   // 3*3*32
constexpr int SUBS = 4;     // i-dimension split factor
constexpr int ISUB = NI / SUBS;        // 72 input caps per (block,sub)
constexpr int NPOS = 4 * SOUT * SOUT;  // 576 output positions
constexpr float EPSF = 1e-9f;
constexpr int CHUNK = 33 * 32;         // per-(n,sub) partial: j*32+o ; j 0..15 S1, 16..31 S2, 32 S0
constexpr size_t POSE_OUT = (size_t)NPOS * OCAP * PD;  // 294912

typedef float v2f __attribute__((ext_vector_type(2)));

__device__ __forceinline__ v2f vfma(v2f a, v2f b, v2f c) { return __builtin_elementwise_fma(a, b, c); }
__device__ __forceinline__ v2f splat(float a) { v2f r; r.x = a; r.y = a; return r; }

// DPP lane exchange (compile-time ctrl); folds into v_add_f32_dpp.
template<int CTRL>
__device__ __forceinline__ float dppf(float x) {
    return __int_as_float(__builtin_amdgcn_update_dpp(0, __float_as_int(x), CTRL, 0xF, 0xF, true));
}
// ds_swizzle xor-16 within 32-lane groups (BitMode: offset = (xor<<10) | and=0x1F)
#define SWZ16(x) __int_as_float(__builtin_amdgcn_ds_swizzle(__float_as_int(x), (16 << 10) | 0x1F))

// 32-lane all-reduce sum (4 DPP levels + 1 swizzle)
__device__ __forceinline__ float redsum32(float x) {
    x += dppf<0xB1>(x);
    x += dppf<0x4E>(x);
    x += dppf<0x141>(x);
    x += dppf<0x140>(x);
    x += SWZ16(x);
    return x;
}

// W fragment as 8 packed pairs over r: W2[q*2+h] = {W[q][2h], W[q][2h+1]}
__device__ __forceinline__ void loadW(const float* __restrict__ p, v2f (&W)[8]) {
    const float4 w0 = *reinterpret_cast<const float4*>(p);
    const float4 w1 = *reinterpret_cast<const float4*>(p + 4);
    const float4 w2 = *reinterpret_cast<const float4*>(p + 8);
    const float4 w3 = *reinterpret_cast<const float4*>(p + 12);
    W[0].x=w0.x; W[0].y=w0.y; W[1].x=w0.z; W[1].y=w0.w;
    W[2].x=w1.x; W[2].y=w1.y; W[3].x=w1.z; W[3].y=w1.w;
    W[4].x=w2.x; W[4].y=w2.y; W[5].x=w2.z; W[5].y=w2.w;
    W[6].x=w3.x; W[6].y=w3.y; W[7].x=w3.z; W[7].y=w3.w;
}

// votes: v[p*2+h] = {votes[p][2h], votes[p][2h+1]} = sum_q P[p][q]*W2[q*2+h]
__device__ __forceinline__ void vote8(const float* __restrict__ pr, const v2f (&W)[8], v2f (&v)[8]) {
    #pragma unroll
    for (int p = 0; p < 4; ++p) {
        const float4 pv = *reinterpret_cast<const float4*>(pr + p * 4);
        #pragma unroll
        for (int h = 0; h < 2; ++h) {
            v2f acc = splat(pv.w) * W[6 + h];
            acc = vfma(splat(pv.z), W[4 + h], acc);
            acc = vfma(splat(pv.y), W[2 + h], acc);
            acc = vfma(splat(pv.x), W[0 + h], acc);
            v[p * 2 + h] = acc;
        }
    }
}

// acc-pair h covers pose dims (2h, 2h+1)
__device__ __forceinline__ constexpr int DH(int h) { return 2 * h; }

// ---------------------------------------------------------------------------
// Sweep: block = (yx, sub) with XCD-locality swizzle (R18, validated: -13MB
// FETCH, -9us total): bid = g*8 + x8; yx = (g>>2)*8 + x8; sub = g&3.
// 4 waves; wave = batch b (shared W stream -> L1 broadcast). lane = (o, half);
// 2 i per wave-step; 36 steps. Stats prologue fused per-wave. W prefetched
// DEPTH-2 via 3-buffer rotation (use buf[s%3], prefetch s+2 into buf[(s+2)%3])
// to cover the ~200-400cy L2 latency that depth-1 left exposed.
// launch_bounds (256,2): VGPR cap 128 >= ~88 needed (k>2 caps below need).
// ---------------------------------------------------------------------------
template<int SWEEP>
__global__ __launch_bounds__(256, 2)
void sweep_kernel(const float* __restrict__ pose_in,   // [4,14,14,32,16]
                  const float* __restrict__ act_in,    // [4,14,14,32]
                  const float* __restrict__ wmat,      // [288,32,16]
                  const float* __restrict__ beta_v,    // [32]
                  const float* __restrict__ beta_a,    // [32]
                  const float* __restrict__ prev,      // partials of sweep-1 (unused if SWEEP==0)
                  float* __restrict__ outbuf)          // partials [n*4+sub][CHUNK]
{
    __shared__ __align__(16) float sP[4 * ISUB * PD]; // 18.4 KB: 4 batches' i-chunks
    __shared__ float sA[4 * ISUB];

    const int bid = blockIdx.x;
    const int x8  = bid & 7;            // target XCD
    const int g   = bid >> 3;           // 0..287
    const int sub = g & 3;
    const int yx  = (g >> 2) * 8 + x8;  // 0..143, yx % 8 == x8
    const int y   = yx / SOUT;
    const int x   = yx % SOUT;

    const int t    = threadIdx.x;
    const int wave = t >> 6;            // 0..3 = batch b
    const int lane = t & 63;
    const int o    = lane & 31;
    const int half = lane >> 5;

    // ---- stage 4 batches' i-chunks (coalesced float4) ----
    {
        const float4* src = reinterpret_cast<const float4*>(pose_in);
        float4* dst = reinterpret_cast<float4*>(sP);
        for (int u = t; u < 4 * ISUB * 4; u += 256) {  // 1152 float4
            const int bs   = u / (ISUB * 4);
            const int r    = u - bs * (ISUB * 4);
            const int il   = r >> 2;
            const int comp = r & 3;
            const int ig   = sub * ISUB + il;
            const int k = ig >> 5, c = ig & 31;
            const int ki = k / 3, kj = k - ki * 3;
            const int cell = (bs * 14 + y + ki) * 14 + (x + kj);
            dst[u] = src[(size_t)(cell * 32 + c) * 4 + comp];
        }
        for (int u = t; u < 4 * ISUB; u += 256) {
            const int bs = u / ISUB;
            const int il = u - bs * ISUB;
            const int ig = sub * ISUB + il;
            const int k = ig >> 5, c = ig & 31;
            const int ki = k / 3, kj = k - ki * 3;
            const int cell = (bs * 14 + y + ki) * 14 + (x + kj);
            sA[u] = act_in[(size_t)cell * 32 + c];
        }
    }

    const int n = wave * (SOUT * SOUT) + yx;

    // ---- fused stats prologue: per-wave, lane (o, half) handles 8 dims ----
    float bias_r = 0.f;
    v2f i2r[8], ngr[8];
    if constexpr (SWEEP > 0) {
        const float* base = prev + (size_t)n * (SUBS * CHUNK);
        float S0 = 0.f, S1[8], S2[8];
        #pragma unroll
        for (int d = 0; d < 8; ++d) { S1[d] = 0.f; S2[d] = 0.f; }
        #pragma unroll
        for (int s = 0; s < SUBS; ++s) {
            const float* c = base + s * CHUNK;
            S0 += c[32 * 32 + o];
            #pragma unroll
            for (int d = 0; d < 8; ++d) {
                S1[d] += c[(half * 8 + d) * 32 + o];
                S2[d] += c[(16 + half * 8 + d) * 32 + o];
            }
        }
        const float inv = 1.f / S0;
        float ll = 0.f, c0 = 0.f;
        v2f i2own[4], ngown[4];
        #pragma unroll
        for (int m = 0; m < 4; ++m) {
            const float m0 = S1[2*m] * inv, m1 = S1[2*m+1] * inv;
            const float v0 = fmaxf(fmaf(-m0, m0, S2[2*m]   * inv), 0.f);
            const float v1 = fmaxf(fmaf(-m1, m1, S2[2*m+1] * inv), 0.f);
            const float i20 = 0.5f / fmaxf(v0, 1e-30f);
            const float i21 = 0.5f / fmaxf(v1, 1e-30f);
            ll += __logf(sqrtf(v0) + EPSF) + __logf(sqrtf(v1) + EPSF);
            c0 += m0 * m0 * i20 + m1 * m1 * i21;
            i2own[m].x = i20;            i2own[m].y = i21;
            ngown[m].x = -2.f * m0 * i20; ngown[m].y = -2.f * m1 * i21;
        }
        ll += __shfl_xor(ll, 32, 64);    // fold the other 8 dims
        c0 += __shfl_xor(c0, 32, 64);
        const float cost = S0 * fmaf(16.f, beta_v[o], ll);
        const float oact = 1.f / (1.f + __expf(-(float)SWEEP * (beta_a[o] - cost)));
        bias_r = __logf(oact + EPSF) - ll - c0;
        // redistribute: every lane needs all 16 dims of its o
        #pragma unroll
        for (int m = 0; m < 4; ++m) {
            v2f oi2, ong;
            oi2.x = __shfl_xor(i2own[m].x, 32, 64);
            oi2.y = __shfl_xor(i2own[m].y, 32, 64);
            ong.x = __shfl_xor(ngown[m].x, 32, 64);
            ong.y = __shfl_xor(ngown[m].y, 32, 64);
            if (half == 0) {
                i2r[m] = i2own[m]; i2r[4+m] = oi2;
                ngr[m] = ngown[m]; ngr[4+m] = ong;
            } else {
                i2r[m] = oi2; i2r[4+m] = i2own[m];
                ngr[m] = ong; ngr[4+m] = ngown[m];
            }
        }
    }
    __syncthreads();

    v2f s1[8], s2[8];
    float s0acc = 0.f;
    #pragma unroll
    for (int h = 0; h < 8; ++h) { s1[h] = splat(0.f); s2[h] = splat(0.f); }

    // W per thread: i = sub*72 + step*2 + half, row (i*32+o)*16; step stride 1024 floats
    const float* wth = wmat + ((size_t)((sub * ISUB + half) * OCAP) + o) * PD;
    const float* pbase = sP + wave * ISUB * PD;
    const float* abase = sA + wave * ISUB;

    // depth-2 prefetch: 3 rotating W buffers
    v2f WA[8], WB[8], WC[8];
    loadW(wth, WA);
    loadW(wth + 1024, WB);

#define STEP(st_, Wc, Wn)                                                  \
    {                                                                      \
        if ((st_) < 34) loadW(wth + (size_t)((st_) + 2) * 1024, Wn);       \
        const int il = (st_) * 2 + half;                                   \
        v2f v[8];                                                          \
        vote8(pbase + il * PD, Wc, v);                                     \
        const float a_i = abase[il];                                       \
        float rrp;                                                         \
        if constexpr (SWEEP == 0) {                                        \
            rrp = a_i * (1.0f / 32.0f);                                    \
        } else {                                                           \
            v2f ts2 = splat(0.f);                                          \
            _Pragma("unroll")                                              \
            for (int h = 0; h < 8; ++h) {                                  \
                const v2f tmp = vfma(v[h], i2r[h], ngr[h]);                \
                ts2 = vfma(v[h], tmp, ts2);                                \
            }                                                              \
            /* shift-invariant softmax, no max-sub (bounded; validated R13) */ \
            const float zz = bias_r - (ts2.x + ts2.y);                     \
            const float e = __expf(zz);                                    \
            const float es = redsum32(e);                                  \
            rrp = __fdividef(e, es) * a_i;                                 \
        }                                                                  \
        s0acc += rrp;                                                      \
        const v2f rr2 = splat(rrp);                                        \
        _Pragma("unroll")                                                  \
        for (int h = 0; h < 8; ++h) {                                      \
            const v2f rv = rr2 * v[h];                                     \
            s1[h] = s1[h] + rv;                                            \
            s2[h] = vfma(rv, v[h], s2[h]);                                 \
        }                                                                  \
    }

    #pragma unroll 1
    for (int kk = 0; kk < 12; ++kk) {
        STEP(3 * kk,     WA, WC);
        STEP(3 * kk + 1, WB, WA);
        STEP(3 * kk + 2, WC, WB);
    }
#undef STEP

    // fold the two halves (different i, same o) within the wave
    #pragma unroll
    for (int h = 0; h < 8; ++h) {
        s1[h].x += __shfl_xor(s1[h].x, 32, 64);
        s1[h].y += __shfl_xor(s1[h].y, 32, 64);
        s2[h].x += __shfl_xor(s2[h].x, 32, 64);
        s2[h].y += __shfl_xor(s2[h].y, 32, 64);
    }
    s0acc += __shfl_xor(s0acc, 32, 64);

    // wave writes its quarter-partial chunk directly (no cross-wave reduction)
    if (half == 0) {
        float* dstc = outbuf + (size_t)(n * SUBS + sub) * CHUNK;
        #pragma unroll
        for (int h = 0; h < 8; ++h) {
            dstc[DH(h) * 32 + o]          = s1[h].x;
            dstc[(DH(h) + 1) * 32 + o]    = s1[h].y;
            dstc[(16 + DH(h)) * 32 + o]   = s2[h].x;
            dstc[(17 + DH(h)) * 32 + o]   = s2[h].y;
        }
        dstc[32 * 32 + o] = s0acc;
    }
}

// final: same XCD-locality mapping -> block for n runs on XCD (n%144)%8,
// where that n's partials live in L2.
__global__ __launch_bounds__(256, 4)
void final_kernel(const float* __restrict__ prev,      // partials of sweep 2
                  const float* __restrict__ beta_v,
                  const float* __restrict__ beta_a,
                  float* __restrict__ out)
{
    const int bid = blockIdx.x;         // 576
    const int x8  = bid & 7;
    const int g   = bid >> 3;           // 0..71
    const int yxi = g % 18;
    const int b   = g / 18;
    const int n   = b * 144 + yxi * 8 + x8;

    const int t  = threadIdx.x;
    const int oo = t >> 3, dp = t & 7, d0 = dp * 2;
    const float* base = prev + (size_t)n * (SUBS * CHUNK);
    float s0 = 0.f, S1a = 0.f, S1b = 0.f, S2a = 0.f, S2b = 0.f;
    #pragma unroll
    for (int s = 0; s < SUBS; ++s) {
        const float* c = base + s * CHUNK;
        s0  += c[32 * 32 + oo];
        S1a += c[(d0)      * 32 + oo];
        S1b += c[(d0 + 1)  * 32 + oo];
        S2a += c[(16 + d0) * 32 + oo];
        S2b += c[(17 + d0) * 32 + oo];
    }
    const float inv = 1.f / s0;
    const float m0 = S1a * inv, m1 = S1b * inv;
    out[(size_t)n * (OCAP * PD) + oo * PD + d0]     = m0;
    out[(size_t)n * (OCAP * PD) + oo * PD + d0 + 1] = m1;

    const float v0 = fmaxf(fmaf(-m0, m0, S2a * inv), 0.f);
    const float v1 = fmaxf(fmaf(-m1, m1, S2b * inv), 0.f);
    float lt = __logf(sqrtf(v0) + EPSF) + __logf(sqrtf(v1) + EPSF);
    lt += __shfl_xor(lt, 1, 8);
    lt += __shfl_xor(lt, 2, 8);
    lt += __shfl_xor(lt, 4, 8);
    if (dp == 0) {
        const float cost = s0 * fmaf(16.f, beta_v[oo], lt);
        const float oact = 1.f / (1.f + __expf(-3.0f * (beta_a[oo] - cost)));  // inv_temp=3 at it=2
        out[POSE_OUT + (size_t)n * OCAP + oo] = oact;
    }
}

} // namespace

extern "C" void kernel_launch(void* const* d_in, const int* in_sizes, int n_in,
                              void* d_out, int out_size, void* d_ws, size_t ws_size,
                              hipStream_t stream) {
    const float* pose_in = (const float*)d_in[0];
    const float* act_in  = (const float*)d_in[1];
    const float* wmat    = (const float*)d_in[2];
    const float* beta_v  = (const float*)d_in[3];
    const float* beta_a  = (const float*)d_in[4];
    float* out = (float*)d_out;

    float* bufA = (float*)d_ws;                       // 9.73 MB
    float* bufB = bufA + (size_t)NPOS * SUBS * CHUNK; // 9.73 MB

    dim3 block(256);
    dim3 gridS(144 * SUBS);    // 576 = 144 yx * 4 sub (XCD-swizzled decode)
    dim3 gridF(NPOS);          // 576 positions (XCD-swizzled decode)

    sweep_kernel<0><<<gridS, block, 0, stream>>>(pose_in, act_in, wmat, beta_v, beta_a, nullptr, bufA);
    sweep_kernel<1><<<gridS, block, 0, stream>>>(pose_in, act_in, wmat, beta_v, beta_a, bufA, bufB);
    sweep_kernel<2><<<gridS, block, 0, stream>>>(pose_in, act_in, wmat, beta_v, beta_a, bufB, bufA);
    final_kernel<<<gridF, block, 0, stream>>>(bufA, beta_v, beta_a, out);
}

// Round 21
// 106.804 us; speedup vs baseline: 1.0337x; 1.0337x over previous
//
#include <hip/hip_runtime.h>
#include <math.h>

namespace {

constexpr int SOUT = 12;    // (14-3)/1+1
constexpr int OCAP = 32;
constexpr int PD   = 16;    // 4x4 pose
constexpr int NI   = 288;   // 3*3*32
constexpr int NPOS = 4 * SOUT * SOUT;  // 576 positions
constexpr float EPSF = 1e-9f;
constexpr size_t POSE_OUT = (size_t)NPOS * OCAP * PD;  // 294912

typedef float v2f __attribute__((ext_vector_type(2)));

__device__ __forceinline__ v2f vfma(v2f a, v2f b, v2f c) { return __builtin_elementwise_fma(a, b, c); }
__device__ __forceinline__ v2f splat(float a) { v2f r; r.x = a; r.y = a; return r; }

// DPP lane exchange (compile-time ctrl); folds into v_add_f32_dpp.
template<int CTRL>
__device__ __forceinline__ float dppf(float x) {
    return __int_as_float(__builtin_amdgcn_update_dpp(0, __float_as_int(x), CTRL, 0xF, 0xF, true));
}
// ds_swizzle xor-16 within 32-lane groups (BitMode: offset = (xor<<10) | and=0x1F)
#define SWZ16(x) __int_as_float(__builtin_amdgcn_ds_swizzle(__float_as_int(x), (16 << 10) | 0x1F))

// 32-lane all-reduce sum (4 DPP levels + 1 swizzle)
__device__ __forceinline__ float redsum32(float x) {
    x += dppf<0xB1>(x);
    x += dppf<0x4E>(x);
    x += dppf<0x141>(x);
    x += dppf<0x140>(x);
    x += SWZ16(x);
    return x;
}

// W row (16 floats) as 8 packed pairs: W[q*2+h] = {Wrow[q*4+2h... ]} see vote8
__device__ __forceinline__ void loadW(const float* __restrict__ p, v2f (&W)[8]) {
    const float4 w0 = *reinterpret_cast<const float4*>(p);
    const float4 w1 = *reinterpret_cast<const float4*>(p + 4);
    const float4 w2 = *reinterpret_cast<const float4*>(p + 8);
    const float4 w3 = *reinterpret_cast<const float4*>(p + 12);
    W[0].x=w0.x; W[0].y=w0.y; W[1].x=w0.z; W[1].y=w0.w;
    W[2].x=w1.x; W[2].y=w1.y; W[3].x=w1.z; W[3].y=w1.w;
    W[4].x=w2.x; W[4].y=w2.y; W[5].x=w2.z; W[5].y=w2.w;
    W[6].x=w3.x; W[6].y=w3.y; W[7].x=w3.z; W[7].y=w3.w;
}

// votes: v[h] holds pose dims (2h, 2h+1)  [h = p*2+hh -> dims 4p+2hh]
__device__ __forceinline__ void vote8(const float* __restrict__ pr, const v2f (&W)[8], v2f (&v)[8]) {
    #pragma unroll
    for (int p = 0; p < 4; ++p) {
        const float4 pv = *reinterpret_cast<const float4*>(pr + p * 4);
        #pragma unroll
        for (int h = 0; h < 2; ++h) {
            v2f acc = splat(pv.w) * W[6 + h];
            acc = vfma(splat(pv.z), W[4 + h], acc);
            acc = vfma(splat(pv.y), W[2 + h], acc);
            acc = vfma(splat(pv.x), W[0 + h], acc);
            v[p * 2 + h] = acc;
        }
    }
}

// ---------------------------------------------------------------------------
// Single fused kernel: one block per output position n. 256 threads = 4 waves.
// lane = (o = t&31); slot = t>>5 (0..7) picks the i-lane; per step the block
// covers 8 i (i = step*8 + slot), 36 steps cover all 288. All 3 EM sweeps run
// in one kernel: stats are reduced block-locally in LDS between sweeps
// (2-phase sRed, validated R16) — no workspace, no partial round-trips, no
// extra dispatches, P/A staged ONCE. Inner loop = R18's validated v2f + DPP
// no-max softmax + reg-cached stats + W ping-pong.
// launch_bounds (256,2): VGPR cap 128 >= ~100 needed (k>2 caps below need).
// ---------------------------------------------------------------------------
__global__ __launch_bounds__(256, 2)
void caps_fused(const float* __restrict__ pose_in,   // [4,14,14,32,16]
                const float* __restrict__ act_in,    // [4,14,14,32]
                const float* __restrict__ wmat,      // [288,32,16]
                const float* __restrict__ beta_v,    // [32]
                const float* __restrict__ beta_a,    // [32]
                float* __restrict__ out)             // pose ++ act
{
    __shared__ __align__(16) float sP[NI * PD];      // 18.4 KB full patch
    __shared__ float sA[NI];
    __shared__ __align__(8) float sStat[OCAP][2 * PD + 2]; // [o][0..15]=i2, [16..31]=ng
    __shared__ float sBias[OCAP];
    __shared__ float sRed[2][33][33];                // 2-phase cross-wave partials

    const int n  = blockIdx.x;
    const int b  = n / (SOUT * SOUT);
    const int yx = n % (SOUT * SOUT);
    const int y  = yx / SOUT;
    const int x  = yx % SOUT;

    const int t    = threadIdx.x;
    const int wave = t >> 6;            // 0..3
    const int o    = t & 31;
    const int slot = t >> 5;            // 0..7
    const int half = slot & 1;

    // ---- stage the full 288-cap patch ONCE (coalesced float4) ----
    {
        const float4* src = reinterpret_cast<const float4*>(pose_in);
        float4* dst = reinterpret_cast<float4*>(sP);
        for (int u = t; u < NI * 4; u += 256) {      // 1152 float4
            const int i = u >> 2, comp = u & 3;
            const int k = i >> 5, c = i & 31;
            const int ki = k / 3, kj = k - ki * 3;
            const int cell = (b * 14 + y + ki) * 14 + (x + kj);
            dst[u] = src[(size_t)(cell * 32 + c) * 4 + comp];
        }
        for (int u = t; u < NI; u += 256) {
            const int k = u >> 5, c = u & 31;
            const int ki = k / 3, kj = k - ki * 3;
            const int cell = (b * 14 + y + ki) * 14 + (x + kj);
            sA[u] = act_in[(size_t)cell * 32 + c];
        }
    }
    __syncthreads();

    // lane W base: i = step*8 + slot, row (i*32+o)*16; step stride 4096 floats
    const float* wth = wmat + ((size_t)(slot * OCAP + o)) * PD;

    #pragma unroll 1
    for (int sweep = 0; sweep < 3; ++sweep) {
        // per-sweep register cache of the per-o stats
        float bias_r = 0.f;
        v2f i2r[8], ngr[8];
        if (sweep > 0) {
            bias_r = sBias[o];
            #pragma unroll
            for (int h = 0; h < 8; ++h) {
                i2r[h] = *reinterpret_cast<const v2f*>(&sStat[o][2 * h]);
                ngr[h] = *reinterpret_cast<const v2f*>(&sStat[o][16 + 2 * h]);
            }
        }

        v2f s1[8], s2[8];
        float s0acc = 0.f;
        #pragma unroll
        for (int h = 0; h < 8; ++h) { s1[h] = splat(0.f); s2[h] = splat(0.f); }

        v2f WA[8], WB[8];
        loadW(wth, WA);

#define STEP(st_, Wc, Wn)                                                  \
        {                                                                  \
            if ((st_) < 35) loadW(wth + (size_t)((st_) + 1) * 4096, Wn);   \
            const int il = (st_) * 8 + slot;                               \
            v2f v[8];                                                      \
            vote8(&sP[il * PD], Wc, v);                                    \
            const float a_i = sA[il];                                      \
            float rrp;                                                     \
            if (sweep == 0) {                                              \
                rrp = a_i * (1.0f / 32.0f);                                \
            } else {                                                       \
                v2f ts2 = splat(0.f);                                      \
                _Pragma("unroll")                                          \
                for (int h = 0; h < 8; ++h) {                              \
                    const v2f tmp = vfma(v[h], i2r[h], ngr[h]);            \
                    ts2 = vfma(v[h], tmp, ts2);                            \
                }                                                          \
                /* shift-invariant softmax, no max-sub (validated R13) */  \
                const float zz = bias_r - (ts2.x + ts2.y);                 \
                const float e = __expf(zz);                                \
                const float es = redsum32(e);                              \
                rrp = __fdividef(e, es) * a_i;                             \
            }                                                              \
            s0acc += rrp;                                                  \
            const v2f rr2 = splat(rrp);                                    \
            _Pragma("unroll")                                              \
            for (int h = 0; h < 8; ++h) {                                  \
                const v2f rv = rr2 * v[h];                                 \
                s1[h] = s1[h] + rv;                                        \
                s2[h] = vfma(rv, v[h], s2[h]);                             \
            }                                                              \
        }

        #pragma unroll 1
        for (int kk = 0; kk < 18; ++kk) {
            STEP(2 * kk,     WA, WB);
            STEP(2 * kk + 1, WB, WA);
        }
#undef STEP

        // fold slot pairs (lane^32: different i, same o) within each wave
        #pragma unroll
        for (int h = 0; h < 8; ++h) {
            s1[h].x += __shfl_xor(s1[h].x, 32, 64);
            s1[h].y += __shfl_xor(s1[h].y, 32, 64);
            s2[h].x += __shfl_xor(s2[h].x, 32, 64);
            s2[h].y += __shfl_xor(s2[h].y, 32, 64);
        }
        s0acc += __shfl_xor(s0acc, 32, 64);

        // two-phase cross-wave reduction into sRed (validated R16)
        if (wave < 2 && half == 0) {
            #pragma unroll
            for (int h = 0; h < 8; ++h) {
                sRed[wave][2 * h][o]          = s1[h].x;
                sRed[wave][2 * h + 1][o]      = s1[h].y;
                sRed[wave][16 + 2 * h][o]     = s2[h].x;
                sRed[wave][16 + 2 * h + 1][o] = s2[h].y;
            }
            sRed[wave][32][o] = s0acc;
        }
        __syncthreads();
        if (wave >= 2 && half == 0) {
            #pragma unroll
            for (int h = 0; h < 8; ++h) {
                sRed[wave - 2][2 * h][o]          += s1[h].x;
                sRed[wave - 2][2 * h + 1][o]      += s1[h].y;
                sRed[wave - 2][16 + 2 * h][o]     += s2[h].x;
                sRed[wave - 2][16 + 2 * h + 1][o] += s2[h].y;
            }
            sRed[wave - 2][32][o] += s0acc;
        }
        __syncthreads();

        // ---- block-local stats (sweep<2) or final output (sweep==2) ----
        {
            const int oo = t >> 3, dp = t & 7, d0 = dp * 2;
            const float S0  = sRed[0][32][oo]      + sRed[1][32][oo];
            const float S1a = sRed[0][d0][oo]      + sRed[1][d0][oo];
            const float S1b = sRed[0][d0 + 1][oo]  + sRed[1][d0 + 1][oo];
            const float S2a = sRed[0][16 + d0][oo] + sRed[1][16 + d0][oo];
            const float S2b = sRed[0][17 + d0][oo] + sRed[1][17 + d0][oo];
            const float inv = 1.f / S0;
            const float m0 = S1a * inv, m1 = S1b * inv;
            const float v0 = fmaxf(fmaf(-m0, m0, S2a * inv), 0.f);
            const float v1 = fmaxf(fmaf(-m1, m1, S2b * inv), 0.f);
            float ll = __logf(sqrtf(v0) + EPSF) + __logf(sqrtf(v1) + EPSF);

            if (sweep < 2) {
                const float i20 = 0.5f / fmaxf(v0, 1e-30f);
                const float i21 = 0.5f / fmaxf(v1, 1e-30f);
                float c0 = m0 * m0 * i20 + m1 * m1 * i21;
                sStat[oo][d0]      = i20;
                sStat[oo][d0 + 1]  = i21;
                sStat[oo][16 + d0] = -2.f * m0 * i20;
                sStat[oo][17 + d0] = -2.f * m1 * i21;
                #pragma unroll
                for (int m = 1; m <= 4; m <<= 1) {
                    ll += __shfl_xor(ll, m, 8);
                    c0 += __shfl_xor(c0, m, 8);
                }
                if (dp == 0) {
                    const float cost = S0 * fmaf(16.f, beta_v[oo], ll);
                    const float invtemp = 1.0f + (float)sweep;   // 1, 2
                    const float oact = 1.f / (1.f + __expf(-invtemp * (beta_a[oo] - cost)));
                    sBias[oo] = __logf(oact + EPSF) - ll - c0;
                }
            } else {
                float2 pv; pv.x = m0; pv.y = m1;
                *reinterpret_cast<float2*>(out + (size_t)n * (OCAP * PD) + oo * PD + d0) = pv;
                #pragma unroll
                for (int m = 1; m <= 4; m <<= 1)
                    ll += __shfl_xor(ll, m, 8);
                if (dp == 0) {
                    const float cost = S0 * fmaf(16.f, beta_v[oo], ll);
                    const float oact = 1.f / (1.f + __expf(-3.0f * (beta_a[oo] - cost)));
                    out[POSE_OUT + (size_t)n * OCAP + oo] = oact;
                }
            }
        }
        __syncthreads();   // sStat/sBias visible; sRed safe to overwrite
    }
}

} // namespace

extern "C" void kernel_launch(void* const* d_in, const int* in_sizes, int n_in,
                              void* d_out, int out_size, void* d_ws, size_t ws_size,
                              hipStream_t stream) {
    const float* pose_in = (const float*)d_in[0];
    const float* act_in  = (const float*)d_in[1];
    const float* wmat    = (const float*)d_in[2];
    const float* beta_v  = (const float*)d_in[3];
    const float* beta_a  = (const float*)d_in[4];
    float* out = (float*)d_out;

    caps_fused<<<dim3(NPOS), dim3(256), 0, stream>>>(
        pose_in, act_in, wmat, beta_v, beta_a, out);
}